// Round 2
// baseline (297.902 us; speedup 1.0000x reference)
//
#include <hip/hip_runtime.h>

#define HWZ 32768   // 64*64*8 spatial positions
#define NH 8
#define HD 16

// workspace layout (float offsets)
#define MU_OFF   0
#define RS_OFF   128
#define Q_OFF    1024
#define K_OFF    (Q_OFF + NH*HWZ*HD)
#define V_OFF    (K_OFF + NH*HWZ*HD)
#define AO_OFF   (V_OFF + NH*HWZ*HD)

// ---------------- per-channel mean / rsqrt(var) ----------------
__global__ void stats_kernel(const float* __restrict__ x, float* __restrict__ ws) {
    int ch = blockIdx.x;
    const float4* xp = (const float4*)(x + (size_t)ch * HWZ);
    float s = 0.f, ss = 0.f;
    for (int i = threadIdx.x; i < HWZ / 4; i += blockDim.x) {
        float4 v = xp[i];
        s  += v.x + v.y + v.z + v.w;
        ss += v.x*v.x + v.y*v.y + v.z*v.z + v.w*v.w;
    }
    for (int off = 32; off; off >>= 1) {
        s  += __shfl_down(s, off);
        ss += __shfl_down(ss, off);
    }
    __shared__ float as_[4], bs_[4];
    int lane = threadIdx.x & 63, wid = threadIdx.x >> 6;
    if (lane == 0) { as_[wid] = s; bs_[wid] = ss; }
    __syncthreads();
    if (threadIdx.x == 0) {
        float S = 0.f, SS = 0.f;
        for (int w = 0; w < 4; w++) { S += as_[w]; SS += bs_[w]; }
        float mu  = S / (float)HWZ;
        float var = SS / (float)HWZ - mu * mu;
        ws[MU_OFF + ch] = mu;
        ws[RS_OFF + ch] = rsqrtf(var + 1e-5f);
    }
}

// ---------------- QKV GEMM with LN folded into staging ----------------
// qkv[p, j] = sum_c xn[c, p] * w_qkv[c, j] + b_qkv[j]
__global__ void qkv_kernel(const float* __restrict__ x,
                           const float* __restrict__ w_qkv,
                           const float* __restrict__ b_qkv,
                           float* __restrict__ ws) {
    __shared__ float xs[128 * 32];
    int p0 = blockIdx.x * 32;
    for (int idx = threadIdx.x; idx < 4096; idx += 384) {
        int c = idx >> 5, pl = idx & 31;
        xs[idx] = (x[(size_t)c * HWZ + p0 + pl] - ws[MU_OFF + c]) * ws[RS_OFF + c];
    }
    __syncthreads();
    int j = threadIdx.x;
    float acc[32];
#pragma unroll
    for (int p = 0; p < 32; p++) acc[p] = 0.f;
    for (int c = 0; c < 128; c++) {
        float w = w_qkv[c * 384 + j];
        const float4* xr = (const float4*)(xs + c * 32);
#pragma unroll
        for (int p4 = 0; p4 < 8; p4++) {
            float4 xv = xr[p4];
            acc[p4*4+0] += xv.x * w;
            acc[p4*4+1] += xv.y * w;
            acc[p4*4+2] += xv.z * w;
            acc[p4*4+3] += xv.w * w;
        }
    }
    float b = b_qkv[j];
    int which = j >> 7;            // 0=q, 1=k, 2=v
    int head  = (j & 127) >> 4;
    int d     = j & 15;
    float* dst = ws + (which == 0 ? Q_OFF : (which == 1 ? K_OFF : V_OFF));
    float scale = (which == 0) ? 0.25f : 1.0f;   // hd^-0.5 = 1/4
    for (int p = 0; p < 32; p++) {
        dst[((size_t)head * HWZ + p0 + p) * 16 + d] = (acc[p] + b) * scale;
    }
}

// ---------------- NATTEN 3x3x3 attention, LDS-tiled ----------------
// block: head x (8h x 8w x 8z) query tile, 512 threads = 1 query each.
// K halo (10x10x8 pos x 16d fp32 = 51.2KB) staged in LDS, then the SAME
// buffer is reused for V. float4 groups XOR-swizzled by (tz&3)^(tw&3).
__global__ __launch_bounds__(512) void attn_kernel(const float* __restrict__ rpb,
                                                   float* __restrict__ ws) {
    __shared__ float kv[800 * 16];   // 51.2 KB
    int blk = blockIdx.x;
    int head = blk >> 6;
    int t = blk & 63;
    int h0 = (t >> 3) * 8, w0 = (t & 7) * 8;
    int tid = threadIdx.x;
    int lh = tid >> 6, lw = (tid >> 3) & 7, lz = tid & 7;
    int gh = h0 + lh, gw = w0 + lw, gz = lz;
    int sh = min(max(gh - 1, 0), 61);
    int sw = min(max(gw - 1, 0), 61);
    int sz = min(max(gz - 1, 0), 5);

    const float* kbase = ws + K_OFF + (size_t)head * HWZ * 16;
    const float* vbase = ws + V_OFF + (size_t)head * HWZ * 16;

    // ---- stage K halo ----
    for (int f4 = tid; f4 < 3200; f4 += 512) {
        int th = f4 / 320;
        int r  = f4 - th * 320;
        int tw = r >> 5;
        int zd = r & 31;
        int tz = zd >> 2, d4 = zd & 3;
        int ghh = min(max(h0 - 1 + th, 0), 63);
        int gww = min(max(w0 - 1 + tw, 0), 63);
        float4 val = *(const float4*)(kbase + (size_t)(ghh * 512 + gww * 8 + tz) * 16 + d4 * 4);
        *(float4*)(kv + ((th * 10 + tw) * 8 + tz) * 16 + ((d4 ^ (tz & 3) ^ (tw & 3)) * 4)) = val;
    }

    // ---- load q (overlaps staging) ----
    float q[16];
    const float* qp = ws + Q_OFF + ((size_t)head * HWZ + (size_t)(gh * 512 + gw * 8 + gz)) * 16;
#pragma unroll
    for (int d4 = 0; d4 < 4; d4++) {
        float4 v = ((const float4*)qp)[d4];
        q[d4*4+0] = v.x; q[d4*4+1] = v.y; q[d4*4+2] = v.z; q[d4*4+3] = v.w;
    }
    __syncthreads();

    // ---- logits ----
    const float* rp = rpb + head * 125 + (sh - gh + 2) * 25 + (sw - gw + 2) * 5 + (sz - gz + 2);
    int bh = sh - (h0 - 1), bw = sw - (w0 - 1);
    float l[27];
    float m = -1e30f;
#pragma unroll
    for (int a = 0; a < 3; a++)
#pragma unroll
    for (int b = 0; b < 3; b++)
#pragma unroll
    for (int c = 0; c < 3; c++) {
        int th = bh + a, tw = bw + b, tz = sz + c;
        int lpos = (th * 10 + tw) * 8 + tz;
        float dot = 0.f;
#pragma unroll
        for (int d4 = 0; d4 < 4; d4++) {
            float4 kvv = *(const float4*)(kv + lpos * 16 + ((d4 ^ (tz & 3) ^ (tw & 3)) * 4));
            dot += q[d4*4+0]*kvv.x + q[d4*4+1]*kvv.y + q[d4*4+2]*kvv.z + q[d4*4+3]*kvv.w;
        }
        float lg = dot + rp[a * 25 + b * 5 + c];
        l[a*9 + b*3 + c] = lg;
        m = fmaxf(m, lg);
    }
    float s = 0.f;
#pragma unroll
    for (int n = 0; n < 27; n++) { l[n] = expf(l[n] - m); s += l[n]; }
    float inv = 1.f / s;

    __syncthreads();   // all K reads done before overwrite

    // ---- stage V halo (same buffer) ----
    for (int f4 = tid; f4 < 3200; f4 += 512) {
        int th = f4 / 320;
        int r  = f4 - th * 320;
        int tw = r >> 5;
        int zd = r & 31;
        int tz = zd >> 2, d4 = zd & 3;
        int ghh = min(max(h0 - 1 + th, 0), 63);
        int gww = min(max(w0 - 1 + tw, 0), 63);
        float4 val = *(const float4*)(vbase + (size_t)(ghh * 512 + gww * 8 + tz) * 16 + d4 * 4);
        *(float4*)(kv + ((th * 10 + tw) * 8 + tz) * 16 + ((d4 ^ (tz & 3) ^ (tw & 3)) * 4)) = val;
    }
    __syncthreads();

    // ---- output ----
    float o[16];
#pragma unroll
    for (int d = 0; d < 16; d++) o[d] = 0.f;
#pragma unroll
    for (int a = 0; a < 3; a++)
#pragma unroll
    for (int b = 0; b < 3; b++)
#pragma unroll
    for (int c = 0; c < 3; c++) {
        int th = bh + a, tw = bw + b, tz = sz + c;
        int lpos = (th * 10 + tw) * 8 + tz;
        float w = l[a*9 + b*3 + c];
#pragma unroll
        for (int d4 = 0; d4 < 4; d4++) {
            float4 vv = *(const float4*)(kv + lpos * 16 + ((d4 ^ (tz & 3) ^ (tw & 3)) * 4));
            o[d4*4+0] += w * vv.x; o[d4*4+1] += w * vv.y;
            o[d4*4+2] += w * vv.z; o[d4*4+3] += w * vv.w;
        }
    }
    float* aop = ws + AO_OFF + (size_t)(gh * 512 + gw * 8 + gz) * 128 + head * 16;
#pragma unroll
    for (int d4 = 0; d4 < 4; d4++) {
        float4 vv;
        vv.x = o[d4*4+0] * inv; vv.y = o[d4*4+1] * inv;
        vv.z = o[d4*4+2] * inv; vv.w = o[d4*4+3] * inv;
        ((float4*)aop)[d4] = vv;
    }
}

// ---------------- output projection ----------------
__global__ void proj_kernel(const float* __restrict__ w_proj,
                            const float* __restrict__ b_proj,
                            const float* __restrict__ ws_c,
                            float* __restrict__ out) {
    __shared__ float as_[32][129];
    int p0 = blockIdx.x * 32;
    const float* ao = ws_c + AO_OFF;
    for (int idx = threadIdx.x; idx < 4096; idx += 256) {
        int pl = idx >> 7, c = idx & 127;
        as_[pl][c] = ao[(size_t)(p0 + pl) * 128 + c];
    }
    __syncthreads();
    int pl = threadIdx.x & 31;
    int cb = (threadIdx.x >> 5) * 16;
    float acc[16];
#pragma unroll
    for (int i = 0; i < 16; i++) acc[i] = b_proj[cb + i];
    for (int cp = 0; cp < 128; cp++) {
        float a = as_[pl][cp];
        const float4* wp = (const float4*)(w_proj + cp * 128 + cb);
#pragma unroll
        for (int i4 = 0; i4 < 4; i4++) {
            float4 w = wp[i4];
            acc[i4*4+0] += a * w.x; acc[i4*4+1] += a * w.y;
            acc[i4*4+2] += a * w.z; acc[i4*4+3] += a * w.w;
        }
    }
#pragma unroll
    for (int i = 0; i < 16; i++) {
        out[(size_t)(cb + i) * HWZ + p0 + pl] = acc[i];
    }
}

extern "C" void kernel_launch(void* const* d_in, const int* in_sizes, int n_in,
                              void* d_out, int out_size, void* d_ws, size_t ws_size,
                              hipStream_t stream) {
    const float* x      = (const float*)d_in[0];
    const float* w_qkv  = (const float*)d_in[1];
    const float* b_qkv  = (const float*)d_in[2];
    const float* rpb    = (const float*)d_in[3];
    const float* w_proj = (const float*)d_in[4];
    const float* b_proj = (const float*)d_in[5];
    float* out = (float*)d_out;
    float* ws  = (float*)d_ws;

    stats_kernel<<<128, 256, 0, stream>>>(x, ws);
    qkv_kernel<<<1024, 384, 0, stream>>>(x, w_qkv, b_qkv, ws);
    attn_kernel<<<512, 512, 0, stream>>>(rpb, ws);
    proj_kernel<<<1024, 256, 0, stream>>>(w_proj, b_proj, ws, out);
}

// Round 3
// 147.440 us; speedup vs baseline: 2.0205x; 2.0205x over previous
//
#include <hip/hip_runtime.h>

#define HWZ 32768   // 64*64*8 spatial positions
#define NH 8
#define HD 16

// workspace layout (float offsets)
#define MU_OFF   0
#define RS_OFF   128
#define Q_OFF    1024
#define K_OFF    (Q_OFF + NH*HWZ*HD)
#define V_OFF    (K_OFF + NH*HWZ*HD)
#define AO_OFF   (V_OFF + NH*HWZ*HD)   // [c][p] layout: 128 x 32768

// ---------------- per-channel mean / rsqrt(var) ----------------
__global__ void stats_kernel(const float* __restrict__ x, float* __restrict__ ws) {
    int ch = blockIdx.x;
    const float4* xp = (const float4*)(x + (size_t)ch * HWZ);
    float s = 0.f, ss = 0.f;
    for (int i = threadIdx.x; i < HWZ / 4; i += blockDim.x) {
        float4 v = xp[i];
        s  += v.x + v.y + v.z + v.w;
        ss += v.x*v.x + v.y*v.y + v.z*v.z + v.w*v.w;
    }
    for (int off = 32; off; off >>= 1) {
        s  += __shfl_down(s, off);
        ss += __shfl_down(ss, off);
    }
    __shared__ float as_[4], bs_[4];
    int lane = threadIdx.x & 63, wid = threadIdx.x >> 6;
    if (lane == 0) { as_[wid] = s; bs_[wid] = ss; }
    __syncthreads();
    if (threadIdx.x == 0) {
        float S = 0.f, SS = 0.f;
        for (int w = 0; w < 4; w++) { S += as_[w]; SS += bs_[w]; }
        float mu  = S / (float)HWZ;
        float var = SS / (float)HWZ - mu * mu;
        ws[MU_OFF + ch] = mu;
        ws[RS_OFF + ch] = rsqrtf(var + 1e-5f);
    }
}

// ---------------- QKV GEMM, register-blocked 8j x 8p per thread ----------------
// qkv[p, j] = sum_c xn[c, p] * w_qkv[c, j] + b_qkv[j]
__global__ __launch_bounds__(384) void qkv_kernel(const float* __restrict__ x,
                                                  const float* __restrict__ w_qkv,
                                                  const float* __restrict__ b_qkv,
                                                  float* __restrict__ ws) {
    __shared__ float xs[128 * 64];   // 32 KB, LN-folded
    int p0 = blockIdx.x * 64;
    for (int i = threadIdx.x; i < 2048; i += 384) {
        int c = i >> 4, p4 = (i & 15) * 4;
        float4 v = *(const float4*)(x + (size_t)c * HWZ + p0 + p4);
        float mu = ws[MU_OFF + c], rs = ws[RS_OFF + c];
        v.x = (v.x - mu) * rs; v.y = (v.y - mu) * rs;
        v.z = (v.z - mu) * rs; v.w = (v.w - mu) * rs;
        *(float4*)(xs + c * 64 + p4) = v;
    }
    __syncthreads();

    int jg = threadIdx.x >> 3;      // 0..47  -> j0 = jg*8
    int pg = threadIdx.x & 7;       // 0..7   -> positions pg*8 .. pg*8+7
    int j0 = jg * 8;
    float4 aL[8], aH[8];            // [p]: d0..3 / d4..7
#pragma unroll
    for (int p = 0; p < 8; p++) { aL[p] = make_float4(0,0,0,0); aH[p] = make_float4(0,0,0,0); }

    for (int c = 0; c < 128; c++) {
        float4 w0 = *(const float4*)(w_qkv + c * 384 + j0);
        float4 w1 = *(const float4*)(w_qkv + c * 384 + j0 + 4);
        const float* xr = xs + c * 64 + pg * 8;
        float4 x0 = *(const float4*)(xr);
        float4 x1 = *(const float4*)(xr + 4);
        float xp[8] = {x0.x,x0.y,x0.z,x0.w,x1.x,x1.y,x1.z,x1.w};
#pragma unroll
        for (int p = 0; p < 8; p++) {
            float xv = xp[p];
            aL[p].x += w0.x * xv; aL[p].y += w0.y * xv;
            aL[p].z += w0.z * xv; aL[p].w += w0.w * xv;
            aH[p].x += w1.x * xv; aH[p].y += w1.y * xv;
            aH[p].z += w1.z * xv; aH[p].w += w1.w * xv;
        }
    }

    int which = j0 >> 7;            // 0=q 1=k 2=v
    int head  = (j0 & 127) >> 4;
    int d0    = j0 & 15;            // 0 or 8
    float4 b0 = *(const float4*)(b_qkv + j0);
    float4 b1 = *(const float4*)(b_qkv + j0 + 4);
    float scale = (which == 0) ? 0.25f : 1.0f;
    float* dst = ws + (which == 0 ? Q_OFF : (which == 1 ? K_OFF : V_OFF)) + (size_t)head * HWZ * 16;
#pragma unroll
    for (int p = 0; p < 8; p++) {
        size_t pp = (size_t)p0 + pg * 8 + p;
        float4 o0, o1;
        o0.x = (aL[p].x + b0.x) * scale; o0.y = (aL[p].y + b0.y) * scale;
        o0.z = (aL[p].z + b0.z) * scale; o0.w = (aL[p].w + b0.w) * scale;
        o1.x = (aH[p].x + b1.x) * scale; o1.y = (aH[p].y + b1.y) * scale;
        o1.z = (aH[p].z + b1.z) * scale; o1.w = (aH[p].w + b1.w) * scale;
        *(float4*)(dst + pp * 16 + d0)     = o0;
        *(float4*)(dst + pp * 16 + d0 + 4) = o1;
    }
}

// ---------------- NATTEN 3x3x3 attention (round-1 structure, [c][p] AO write) ----------------
__global__ void attn_kernel(const float* __restrict__ rpb, float* __restrict__ ws) {
    int g = blockIdx.x * 256 + threadIdx.x;
    int p = g & (HWZ - 1);
    int head = g >> 15;
    int zi = p & 7, wi = (p >> 3) & 63, hi = p >> 9;
    int sh = min(max(hi - 1, 0), 61);
    int sw = min(max(wi - 1, 0), 61);
    int sz = min(max(zi - 1, 0), 5);

    const float* qp = ws + Q_OFF + ((size_t)head * HWZ + p) * 16;
    float q[16];
#pragma unroll
    for (int d4 = 0; d4 < 4; d4++) {
        float4 v = ((const float4*)qp)[d4];
        q[d4*4+0] = v.x; q[d4*4+1] = v.y; q[d4*4+2] = v.z; q[d4*4+3] = v.w;
    }
    const float* kbase = ws + K_OFF + (size_t)head * HWZ * 16;
    const float* vbase = ws + V_OFF + (size_t)head * HWZ * 16;
    const float* rp = rpb + head * 125 + (sh - hi + 2) * 25 + (sw - wi + 2) * 5 + (sz - zi + 2);

    float l[27];
    float m = -1e30f;
#pragma unroll
    for (int a = 0; a < 3; a++)
#pragma unroll
    for (int b = 0; b < 3; b++)
#pragma unroll
    for (int c = 0; c < 3; c++) {
        int np_ = (sh + a) * 512 + (sw + b) * 8 + (sz + c);
        const float4* kp = (const float4*)(kbase + (size_t)np_ * 16);
        float dot = 0.f;
#pragma unroll
        for (int d4 = 0; d4 < 4; d4++) {
            float4 kv = kp[d4];
            dot += q[d4*4+0]*kv.x + q[d4*4+1]*kv.y + q[d4*4+2]*kv.z + q[d4*4+3]*kv.w;
        }
        float lg = dot + rp[a * 25 + b * 5 + c];
        l[a*9 + b*3 + c] = lg;
        m = fmaxf(m, lg);
    }
    float s = 0.f;
#pragma unroll
    for (int n = 0; n < 27; n++) { l[n] = expf(l[n] - m); s += l[n]; }
    float inv = 1.f / s;

    float o[16];
#pragma unroll
    for (int d = 0; d < 16; d++) o[d] = 0.f;
#pragma unroll
    for (int a = 0; a < 3; a++)
#pragma unroll
    for (int b = 0; b < 3; b++)
#pragma unroll
    for (int c = 0; c < 3; c++) {
        int np_ = (sh + a) * 512 + (sw + b) * 8 + (sz + c);
        const float4* vp = (const float4*)(vbase + (size_t)np_ * 16);
        float w = l[a*9 + b*3 + c];
#pragma unroll
        for (int d4 = 0; d4 < 4; d4++) {
            float4 vv = vp[d4];
            o[d4*4+0] += w * vv.x; o[d4*4+1] += w * vv.y;
            o[d4*4+2] += w * vv.z; o[d4*4+3] += w * vv.w;
        }
    }
    // AO in [c][p] layout: 16 coalesced scalar stores
    float* ao = ws + AO_OFF + (size_t)(head * 16) * HWZ + p;
#pragma unroll
    for (int d = 0; d < 16; d++) {
        ao[(size_t)d * HWZ] = o[d] * inv;
    }
}

// ---------------- output projection: out[c][p] = sum_c' ao[c'][p] * w_proj[c'][c] + b ----------------
// w_proj + AO tile staged in LDS (two 64-row halves, 64KB total)
__global__ __launch_bounds__(256) void proj_kernel(const float* __restrict__ w_proj,
                                                   const float* __restrict__ b_proj,
                                                   const float* __restrict__ ws_c,
                                                   float* __restrict__ out) {
    __shared__ float wl[64 * 128];   // 32 KB: w_proj rows (c' half) x 128 c
    __shared__ float al[64 * 128];   // 32 KB: ao rows (c' half) x 128 p
    int p0 = blockIdx.x * 128;
    int pg = threadIdx.x & 31;       // p_base = pg*4
    int cg = threadIdx.x >> 5;       // c_base = cg*16
    int cb = cg * 16;
    const float* ao = ws_c + AO_OFF;

    float4 acc[16];                  // [ci]: float4 over 4 positions
#pragma unroll
    for (int i = 0; i < 16; i++) acc[i] = make_float4(0,0,0,0);

    for (int half = 0; half < 2; half++) {
        int ch0 = half * 64;
        for (int i = threadIdx.x; i < 2048; i += 256) {
            int r = i >> 5, q4 = (i & 31) * 4;
            *(float4*)(wl + r * 128 + q4) = *(const float4*)(w_proj + (size_t)(ch0 + r) * 128 + q4);
            *(float4*)(al + r * 128 + q4) = *(const float4*)(ao + (size_t)(ch0 + r) * HWZ + p0 + q4);
        }
        __syncthreads();
        for (int cp = 0; cp < 64; cp++) {
            float4 a4 = *(const float4*)(al + cp * 128 + pg * 4);
            float4 w0 = *(const float4*)(wl + cp * 128 + cb);
            float4 w1 = *(const float4*)(wl + cp * 128 + cb + 4);
            float4 w2 = *(const float4*)(wl + cp * 128 + cb + 8);
            float4 w3 = *(const float4*)(wl + cp * 128 + cb + 12);
            float wv[16] = {w0.x,w0.y,w0.z,w0.w, w1.x,w1.y,w1.z,w1.w,
                            w2.x,w2.y,w2.z,w2.w, w3.x,w3.y,w3.z,w3.w};
#pragma unroll
            for (int i = 0; i < 16; i++) {
                acc[i].x += a4.x * wv[i]; acc[i].y += a4.y * wv[i];
                acc[i].z += a4.z * wv[i]; acc[i].w += a4.w * wv[i];
            }
        }
        __syncthreads();
    }
#pragma unroll
    for (int i = 0; i < 16; i++) {
        float b = b_proj[cb + i];
        float4 o = acc[i];
        o.x += b; o.y += b; o.z += b; o.w += b;
        *(float4*)(out + (size_t)(cb + i) * HWZ + p0 + pg * 4) = o;
    }
}

extern "C" void kernel_launch(void* const* d_in, const int* in_sizes, int n_in,
                              void* d_out, int out_size, void* d_ws, size_t ws_size,
                              hipStream_t stream) {
    const float* x      = (const float*)d_in[0];
    const float* w_qkv  = (const float*)d_in[1];
    const float* b_qkv  = (const float*)d_in[2];
    const float* rpb    = (const float*)d_in[3];
    const float* w_proj = (const float*)d_in[4];
    const float* b_proj = (const float*)d_in[5];
    float* out = (float*)d_out;
    float* ws  = (float*)d_ws;

    stats_kernel<<<128, 256, 0, stream>>>(x, ws);
    qkv_kernel<<<512, 384, 0, stream>>>(x, w_qkv, b_qkv, ws);
    attn_kernel<<<1024, 256, 0, stream>>>(rpb, ws);
    proj_kernel<<<256, 256, 0, stream>>>(w_proj, b_proj, ws, out);
}

// Round 4
// 102.806 us; speedup vs baseline: 2.8977x; 1.4342x over previous
//
#include <hip/hip_runtime.h>

#define HWZ 32768   // 64*64*8 spatial positions
#define NH 8
#define HD 16

typedef __bf16 bf16x8 __attribute__((ext_vector_type(8)));
typedef unsigned short u16x8 __attribute__((ext_vector_type(8)));
typedef float f32x4 __attribute__((ext_vector_type(4)));

// ws layout: floats [MU(128) | RS(128) | ... | AO (128*HWZ) ] then bf16 QKV region
#define MU_OFF 0
#define RS_OFF 128
#define AO_OFF 1024
#define QKV_F_OFF (AO_OFF + 128 * HWZ)      // float offset where bf16 region starts
#define HEADSZ (HWZ * 16)                    // ushorts per head
#define REGSZ  (NH * HEADSZ)                 // ushorts per tensor (q/k/v)

__device__ __forceinline__ unsigned short f2bf(float f) {
    unsigned int u = __builtin_bit_cast(unsigned int, f);
    unsigned int r = u + 0x7FFFu + ((u >> 16) & 1u);   // RNE
    return (unsigned short)(r >> 16);
}
__device__ __forceinline__ float bf2f(unsigned short s) {
    unsigned int u = ((unsigned int)s) << 16;
    return __builtin_bit_cast(float, u);
}

// ---------------- per-channel mean / rsqrt(var) ----------------
__global__ void stats_kernel(const float* __restrict__ x, float* __restrict__ ws) {
    int ch = blockIdx.x;
    const float4* xp = (const float4*)(x + (size_t)ch * HWZ);
    float s = 0.f, ss = 0.f;
    for (int i = threadIdx.x; i < HWZ / 4; i += blockDim.x) {
        float4 v = xp[i];
        s  += v.x + v.y + v.z + v.w;
        ss += v.x*v.x + v.y*v.y + v.z*v.z + v.w*v.w;
    }
    for (int off = 32; off; off >>= 1) {
        s  += __shfl_down(s, off);
        ss += __shfl_down(ss, off);
    }
    __shared__ float as_[4], bs_[4];
    int lane = threadIdx.x & 63, wid = threadIdx.x >> 6;
    if (lane == 0) { as_[wid] = s; bs_[wid] = ss; }
    __syncthreads();
    if (threadIdx.x == 0) {
        float S = 0.f, SS = 0.f;
        for (int w = 0; w < 4; w++) { S += as_[w]; SS += bs_[w]; }
        float mu  = S / (float)HWZ;
        float var = SS / (float)HWZ - mu * mu;
        ws[MU_OFF + ch] = mu;
        ws[RS_OFF + ch] = rsqrtf(var + 1e-5f);
    }
}

// ---------------- QKV GEMM via bf16 MFMA ----------------
// out[p][j] = sum_c xn[p][c] * w[c][j] + b[j]; A = xn (16x32 frag), B = w (32x16 frag)
// Block: 512 thr (8 waves), 64 positions, all 384 j in 3 chunks of 128.
__global__ __launch_bounds__(512) void qkv_kernel(const float* __restrict__ x,
                                                  const float* __restrict__ w_qkv,
                                                  const float* __restrict__ b_qkv,
                                                  float* __restrict__ ws) {
    __shared__ unsigned short xs[64 * 128];    // [p][c] bf16, 16B groups XOR-swizzled by p&15
    __shared__ unsigned short wl[128 * 128];   // [j][c] bf16, swizzled by j&15
    const int tid = threadIdx.x;
    const int p0 = blockIdx.x * 64;

    // stage x tile with LN fold: 128c x 64p
#pragma unroll
    for (int it = 0; it < 4; it++) {
        int i = tid + it * 512;
        int c = i >> 4, pq = (i & 15) * 4;
        float mu = ws[MU_OFF + c], rs = ws[RS_OFF + c];
        float4 v = *(const float4*)(x + (size_t)c * HWZ + p0 + pq);
        int c8 = c >> 3, cl = c & 7;
        float vv[4] = {v.x, v.y, v.z, v.w};
#pragma unroll
        for (int e = 0; e < 4; e++) {
            int p = pq + e;
            xs[p * 128 + ((c8 ^ (p & 15)) << 3) + cl] = f2bf((vv[e] - mu) * rs);
        }
    }

    const int wv   = tid >> 6;        // wave 0..7
    const int lane = tid & 63;
    const int col  = lane & 15;
    const int kgrp = lane >> 4;       // 0..3
    const int ptile = wv & 3;         // 16-row p tile
    const int jq    = wv >> 2;        // 0/1: j half within chunk
    const unsigned short* arow = xs + (ptile * 16 + col) * 128;
    const int arow15 = (ptile * 16 + col) & 15;

    unsigned short* qkvb = (unsigned short*)(ws + QKV_F_OFF);

    for (int chunk = 0; chunk < 3; chunk++) {
        if (chunk) __syncthreads();   // previous compute done reading wl
        // stage w chunk: 128c x 128j fp32 -> wl[j][c]
#pragma unroll
        for (int it = 0; it < 8; it++) {
            int i = tid + it * 512;
            int c = i >> 5, jg = (i & 31) * 4;
            float4 w4 = *(const float4*)(w_qkv + (size_t)c * 384 + chunk * 128 + jg);
            int c8 = c >> 3, cl = c & 7;
            float wv4[4] = {w4.x, w4.y, w4.z, w4.w};
#pragma unroll
            for (int e = 0; e < 4; e++) {
                int jl = jg + e;
                wl[jl * 128 + ((c8 ^ (jl & 15)) << 3) + cl] = f2bf(wv4[e]);
            }
        }
        __syncthreads();

        // A fragments (reused across j tiles)
        u16x8 a[4];
#pragma unroll
        for (int ks = 0; ks < 4; ks++) {
            a[ks] = *(const u16x8*)(arow + (((ks * 4 + kgrp) ^ arow15) << 3));
        }

        float scale = (chunk == 0) ? 0.25f : 1.0f;
        unsigned short* dstbase = qkvb + (size_t)chunk * REGSZ;

#pragma unroll
        for (int jt = 0; jt < 4; jt++) {
            int jl = jq * 64 + jt * 16 + col;
            const unsigned short* brow = wl + jl * 128;
            int jl15 = jl & 15;
            f32x4 acc = {0.f, 0.f, 0.f, 0.f};
#pragma unroll
            for (int ks = 0; ks < 4; ks++) {
                u16x8 b = *(const u16x8*)(brow + (((ks * 4 + kgrp) ^ jl15) << 3));
                acc = __builtin_amdgcn_mfma_f32_16x16x32_bf16(
                        __builtin_bit_cast(bf16x8, a[ks]),
                        __builtin_bit_cast(bf16x8, b), acc, 0, 0, 0);
            }
            int head = jq * 4 + jt;
            float bias = b_qkv[chunk * 128 + head * 16 + col];
            unsigned short* dst = dstbase + (size_t)head * HEADSZ + col;
#pragma unroll
            for (int i = 0; i < 4; i++) {
                int p = p0 + ptile * 16 + kgrp * 4 + i;
                dst[(size_t)p * 16] = f2bf((acc[i] + bias) * scale);
            }
        }
    }
}

// ---------------- NATTEN 3x3x3 attention, bf16 Q/K/V ----------------
__global__ void attn_kernel(const float* __restrict__ rpb, float* __restrict__ ws) {
    int g = blockIdx.x * 256 + threadIdx.x;
    int p = g & (HWZ - 1);
    int head = g >> 15;
    int zi = p & 7, wi = (p >> 3) & 63, hi = p >> 9;
    int sh = min(max(hi - 1, 0), 61);
    int sw = min(max(wi - 1, 0), 61);
    int sz = min(max(zi - 1, 0), 5);

    const unsigned short* qkvb = (const unsigned short*)(ws + QKV_F_OFF);
    const unsigned short* qp = qkvb + (size_t)head * HEADSZ + (size_t)p * 16;
    float q[16];
#pragma unroll
    for (int h8 = 0; h8 < 2; h8++) {
        u16x8 v = *(const u16x8*)(qp + h8 * 8);
#pragma unroll
        for (int e = 0; e < 8; e++) q[h8 * 8 + e] = bf2f(v[e]);
    }
    const unsigned short* kbase = qkvb + REGSZ + (size_t)head * HEADSZ;
    const unsigned short* vbase = qkvb + 2 * (size_t)REGSZ + (size_t)head * HEADSZ;
    const float* rp = rpb + head * 125 + (sh - hi + 2) * 25 + (sw - wi + 2) * 5 + (sz - zi + 2);

    float l[27];
    float m = -1e30f;
#pragma unroll
    for (int a = 0; a < 3; a++)
#pragma unroll
    for (int b = 0; b < 3; b++)
#pragma unroll
    for (int c = 0; c < 3; c++) {
        int np_ = (sh + a) * 512 + (sw + b) * 8 + (sz + c);
        const unsigned short* kp = kbase + (size_t)np_ * 16;
        float dot = 0.f;
#pragma unroll
        for (int h8 = 0; h8 < 2; h8++) {
            u16x8 kv = *(const u16x8*)(kp + h8 * 8);
#pragma unroll
            for (int e = 0; e < 8; e++) dot += q[h8 * 8 + e] * bf2f(kv[e]);
        }
        float lg = dot + rp[a * 25 + b * 5 + c];
        l[a*9 + b*3 + c] = lg;
        m = fmaxf(m, lg);
    }
    float s = 0.f;
#pragma unroll
    for (int n = 0; n < 27; n++) { l[n] = expf(l[n] - m); s += l[n]; }
    float inv = 1.f / s;

    float o[16];
#pragma unroll
    for (int d = 0; d < 16; d++) o[d] = 0.f;
#pragma unroll
    for (int a = 0; a < 3; a++)
#pragma unroll
    for (int b = 0; b < 3; b++)
#pragma unroll
    for (int c = 0; c < 3; c++) {
        int np_ = (sh + a) * 512 + (sw + b) * 8 + (sz + c);
        const unsigned short* vp = vbase + (size_t)np_ * 16;
        float w = l[a*9 + b*3 + c];
#pragma unroll
        for (int h8 = 0; h8 < 2; h8++) {
            u16x8 vv = *(const u16x8*)(vp + h8 * 8);
#pragma unroll
            for (int e = 0; e < 8; e++) o[h8 * 8 + e] += w * bf2f(vv[e]);
        }
    }
    float* ao = ws + AO_OFF + (size_t)(head * 16) * HWZ + p;
#pragma unroll
    for (int d = 0; d < 16; d++) {
        ao[(size_t)d * HWZ] = o[d] * inv;
    }
}

// ---------------- output projection ----------------
__global__ __launch_bounds__(256) void proj_kernel(const float* __restrict__ w_proj,
                                                   const float* __restrict__ b_proj,
                                                   const float* __restrict__ ws_c,
                                                   float* __restrict__ out) {
    __shared__ float wl[64 * 128];
    __shared__ float al[64 * 128];
    int p0 = blockIdx.x * 128;
    int pg = threadIdx.x & 31;
    int cg = threadIdx.x >> 5;
    int cb = cg * 16;
    const float* ao = ws_c + AO_OFF;

    float4 acc[16];
#pragma unroll
    for (int i = 0; i < 16; i++) acc[i] = make_float4(0,0,0,0);

    for (int half = 0; half < 2; half++) {
        int ch0 = half * 64;
        for (int i = threadIdx.x; i < 2048; i += 256) {
            int r = i >> 5, q4 = (i & 31) * 4;
            *(float4*)(wl + r * 128 + q4) = *(const float4*)(w_proj + (size_t)(ch0 + r) * 128 + q4);
            *(float4*)(al + r * 128 + q4) = *(const float4*)(ao + (size_t)(ch0 + r) * HWZ + p0 + q4);
        }
        __syncthreads();
        for (int cp = 0; cp < 64; cp++) {
            float4 a4 = *(const float4*)(al + cp * 128 + pg * 4);
            float4 w0 = *(const float4*)(wl + cp * 128 + cb);
            float4 w1 = *(const float4*)(wl + cp * 128 + cb + 4);
            float4 w2 = *(const float4*)(wl + cp * 128 + cb + 8);
            float4 w3 = *(const float4*)(wl + cp * 128 + cb + 12);
            float wv[16] = {w0.x,w0.y,w0.z,w0.w, w1.x,w1.y,w1.z,w1.w,
                            w2.x,w2.y,w2.z,w2.w, w3.x,w3.y,w3.z,w3.w};
#pragma unroll
            for (int i = 0; i < 16; i++) {
                acc[i].x += a4.x * wv[i]; acc[i].y += a4.y * wv[i];
                acc[i].z += a4.z * wv[i]; acc[i].w += a4.w * wv[i];
            }
        }
        __syncthreads();
    }
#pragma unroll
    for (int i = 0; i < 16; i++) {
        float b = b_proj[cb + i];
        float4 o = acc[i];
        o.x += b; o.y += b; o.z += b; o.w += b;
        *(float4*)(out + (size_t)(cb + i) * HWZ + p0 + pg * 4) = o;
    }
}

extern "C" void kernel_launch(void* const* d_in, const int* in_sizes, int n_in,
                              void* d_out, int out_size, void* d_ws, size_t ws_size,
                              hipStream_t stream) {
    const float* x      = (const float*)d_in[0];
    const float* w_qkv  = (const float*)d_in[1];
    const float* b_qkv  = (const float*)d_in[2];
    const float* rpb    = (const float*)d_in[3];
    const float* w_proj = (const float*)d_in[4];
    const float* b_proj = (const float*)d_in[5];
    float* out = (float*)d_out;
    float* ws  = (float*)d_ws;

    stats_kernel<<<128, 256, 0, stream>>>(x, ws);
    qkv_kernel<<<512, 512, 0, stream>>>(x, w_qkv, b_qkv, ws);
    attn_kernel<<<1024, 256, 0, stream>>>(rpb, ws);
    proj_kernel<<<256, 256, 0, stream>>>(w_proj, b_proj, ws, out);
}

// Round 5
// 87.634 us; speedup vs baseline: 3.3994x; 1.1731x over previous
//
#include <hip/hip_runtime.h>

#define HWZ 32768   // 64*64*8 spatial positions
#define NH 8
#define HD 16

typedef __bf16 bf16x8 __attribute__((ext_vector_type(8)));
typedef unsigned short u16x8 __attribute__((ext_vector_type(8)));
typedef float f32x4 __attribute__((ext_vector_type(4)));

// ws layout: floats [MU(128) | RS(128) | pad ] then bf16 QKV region, then bf16 w_proj^T
#define MU_OFF 0
#define RS_OFF 128
#define QKV_F_OFF 1024                       // float offset where bf16 region starts
#define HEADSZ (HWZ * 16)                    // ushorts per head
#define REGSZ  (NH * HEADSZ)                 // ushorts per tensor (q/k/v)
#define WT_F_OFF (QKV_F_OFF + (3 * REGSZ) / 2)   // bf16 w_proj^T image (16384 ushorts)

__device__ __forceinline__ unsigned short f2bf(float f) {
    unsigned int u = __builtin_bit_cast(unsigned int, f);
    unsigned int r = u + 0x7FFFu + ((u >> 16) & 1u);   // RNE
    return (unsigned short)(r >> 16);
}
__device__ __forceinline__ float bf2f(unsigned short s) {
    unsigned int u = ((unsigned int)s) << 16;
    return __builtin_bit_cast(float, u);
}

// ---------------- per-channel mean / rsqrt(var) ----------------
__global__ void stats_kernel(const float* __restrict__ x, float* __restrict__ ws) {
    int ch = blockIdx.x;
    const float4* xp = (const float4*)(x + (size_t)ch * HWZ);
    float s = 0.f, ss = 0.f;
    for (int i = threadIdx.x; i < HWZ / 4; i += blockDim.x) {
        float4 v = xp[i];
        s  += v.x + v.y + v.z + v.w;
        ss += v.x*v.x + v.y*v.y + v.z*v.z + v.w*v.w;
    }
    for (int off = 32; off; off >>= 1) {
        s  += __shfl_down(s, off);
        ss += __shfl_down(ss, off);
    }
    __shared__ float as_[4], bs_[4];
    int lane = threadIdx.x & 63, wid = threadIdx.x >> 6;
    if (lane == 0) { as_[wid] = s; bs_[wid] = ss; }
    __syncthreads();
    if (threadIdx.x == 0) {
        float S = 0.f, SS = 0.f;
        for (int w = 0; w < 4; w++) { S += as_[w]; SS += bs_[w]; }
        float mu  = S / (float)HWZ;
        float var = SS / (float)HWZ - mu * mu;
        ws[MU_OFF + ch] = mu;
        ws[RS_OFF + ch] = rsqrtf(var + 1e-5f);
    }
}

// ---------------- pre-transpose w_proj -> bf16 [j][c'] swizzled image ----------------
__global__ void wprep_kernel(const float* __restrict__ w_proj, float* __restrict__ ws) {
    unsigned short* wt = (unsigned short*)(ws + WT_F_OFF);
    int j  = blockIdx.x;       // 0..127
    int cp = threadIdx.x;      // 0..127
    float w = w_proj[(size_t)cp * 128 + j];
    wt[j * 128 + (((cp >> 3) ^ (j & 15)) << 3) + (cp & 7)] = f2bf(w);
}

// ---------------- QKV GEMM via bf16 MFMA ----------------
__global__ __launch_bounds__(512) void qkv_kernel(const float* __restrict__ x,
                                                  const float* __restrict__ w_qkv,
                                                  const float* __restrict__ b_qkv,
                                                  float* __restrict__ ws) {
    __shared__ unsigned short xs[64 * 128];    // [p][c] bf16, 16B groups XOR-swizzled by p&15
    __shared__ unsigned short wl[128 * 128];   // [j][c] bf16, swizzled by j&15
    const int tid = threadIdx.x;
    const int p0 = blockIdx.x * 64;

#pragma unroll
    for (int it = 0; it < 4; it++) {
        int i = tid + it * 512;
        int c = i >> 4, pq = (i & 15) * 4;
        float mu = ws[MU_OFF + c], rs = ws[RS_OFF + c];
        float4 v = *(const float4*)(x + (size_t)c * HWZ + p0 + pq);
        int c8 = c >> 3, cl = c & 7;
        float vv[4] = {v.x, v.y, v.z, v.w};
#pragma unroll
        for (int e = 0; e < 4; e++) {
            int p = pq + e;
            xs[p * 128 + ((c8 ^ (p & 15)) << 3) + cl] = f2bf((vv[e] - mu) * rs);
        }
    }

    const int wv   = tid >> 6;
    const int lane = tid & 63;
    const int col  = lane & 15;
    const int kgrp = lane >> 4;
    const int ptile = wv & 3;
    const int jq    = wv >> 2;
    const unsigned short* arow = xs + (ptile * 16 + col) * 128;
    const int arow15 = (ptile * 16 + col) & 15;

    unsigned short* qkvb = (unsigned short*)(ws + QKV_F_OFF);

    for (int chunk = 0; chunk < 3; chunk++) {
        if (chunk) __syncthreads();
#pragma unroll
        for (int it = 0; it < 8; it++) {
            int i = tid + it * 512;
            int c = i >> 5, jg = (i & 31) * 4;
            float4 w4 = *(const float4*)(w_qkv + (size_t)c * 384 + chunk * 128 + jg);
            int c8 = c >> 3, cl = c & 7;
            float wv4[4] = {w4.x, w4.y, w4.z, w4.w};
#pragma unroll
            for (int e = 0; e < 4; e++) {
                int jl = jg + e;
                wl[jl * 128 + ((c8 ^ (jl & 15)) << 3) + cl] = f2bf(wv4[e]);
            }
        }
        __syncthreads();

        u16x8 a[4];
#pragma unroll
        for (int ks = 0; ks < 4; ks++) {
            a[ks] = *(const u16x8*)(arow + (((ks * 4 + kgrp) ^ arow15) << 3));
        }

        float scale = (chunk == 0) ? 0.25f : 1.0f;
        unsigned short* dstbase = qkvb + (size_t)chunk * REGSZ;

#pragma unroll
        for (int jt = 0; jt < 4; jt++) {
            int jl = jq * 64 + jt * 16 + col;
            const unsigned short* brow = wl + jl * 128;
            int jl15 = jl & 15;
            f32x4 acc = {0.f, 0.f, 0.f, 0.f};
#pragma unroll
            for (int ks = 0; ks < 4; ks++) {
                u16x8 b = *(const u16x8*)(brow + (((ks * 4 + kgrp) ^ jl15) << 3));
                acc = __builtin_amdgcn_mfma_f32_16x16x32_bf16(
                        __builtin_bit_cast(bf16x8, a[ks]),
                        __builtin_bit_cast(bf16x8, b), acc, 0, 0, 0);
            }
            int head = jq * 4 + jt;
            float bias = b_qkv[chunk * 128 + head * 16 + col];
            unsigned short* dst = dstbase + (size_t)head * HEADSZ + col;
#pragma unroll
            for (int i = 0; i < 4; i++) {
                int p = p0 + ptile * 16 + kgrp * 4 + i;
                dst[(size_t)p * 16] = f2bf((acc[i] + bias) * scale);
            }
        }
    }
}

// ---------------- fused NATTEN attention + output projection ----------------
// block: 256 thr = 32 positions x 8 heads. Attention per thread (27-neighbor
// gathers via L1/L2), o -> bf16 LDS [pl][c]; then proj GEMM via MFMA against
// LDS-staged w_proj^T; out[c][p] fp32.
__global__ __launch_bounds__(256) void attnproj_kernel(const float* __restrict__ rpb,
                                                       const float* __restrict__ b_proj,
                                                       float* __restrict__ ws,
                                                       float* __restrict__ out) {
    __shared__ unsigned short aol[32 * 128];   // 8 KB
    __shared__ unsigned short wl[128 * 128];   // 32 KB
    const int tid = threadIdx.x;
    const int p0 = blockIdx.x * 32;
    const int pl = tid & 31, head = tid >> 5;
    const int p = p0 + pl;
    int zi = p & 7, wi = (p >> 3) & 63, hi = p >> 9;
    int sh = min(max(hi - 1, 0), 61);
    int sw = min(max(wi - 1, 0), 61);
    int sz = min(max(zi - 1, 0), 5);

    const unsigned short* qkvb = (const unsigned short*)(ws + QKV_F_OFF);
    const unsigned short* qp = qkvb + (size_t)head * HEADSZ + (size_t)p * 16;
    float q[16];
#pragma unroll
    for (int h8 = 0; h8 < 2; h8++) {
        u16x8 v = *(const u16x8*)(qp + h8 * 8);
#pragma unroll
        for (int e = 0; e < 8; e++) q[h8 * 8 + e] = bf2f(v[e]);
    }
    const unsigned short* kbase = qkvb + REGSZ + (size_t)head * HEADSZ;
    const unsigned short* vbase = qkvb + 2 * (size_t)REGSZ + (size_t)head * HEADSZ;
    const float* rp = rpb + head * 125 + (sh - hi + 2) * 25 + (sw - wi + 2) * 5 + (sz - zi + 2);

    float l[27];
    float m = -1e30f;
#pragma unroll
    for (int a = 0; a < 3; a++)
#pragma unroll
    for (int b = 0; b < 3; b++)
#pragma unroll
    for (int c = 0; c < 3; c++) {
        int np_ = (sh + a) * 512 + (sw + b) * 8 + (sz + c);
        const unsigned short* kp = kbase + (size_t)np_ * 16;
        float dot = 0.f;
#pragma unroll
        for (int h8 = 0; h8 < 2; h8++) {
            u16x8 kv = *(const u16x8*)(kp + h8 * 8);
#pragma unroll
            for (int e = 0; e < 8; e++) dot += q[h8 * 8 + e] * bf2f(kv[e]);
        }
        float lg = dot + rp[a * 25 + b * 5 + c];
        l[a*9 + b*3 + c] = lg;
        m = fmaxf(m, lg);
    }
    float s = 0.f;
#pragma unroll
    for (int n = 0; n < 27; n++) { l[n] = expf(l[n] - m); s += l[n]; }
    float inv = 1.f / s;

    float o[16];
#pragma unroll
    for (int d = 0; d < 16; d++) o[d] = 0.f;
#pragma unroll
    for (int a = 0; a < 3; a++)
#pragma unroll
    for (int b = 0; b < 3; b++)
#pragma unroll
    for (int c = 0; c < 3; c++) {
        int np_ = (sh + a) * 512 + (sw + b) * 8 + (sz + c);
        const unsigned short* vp = vbase + (size_t)np_ * 16;
        float w = l[a*9 + b*3 + c];
#pragma unroll
        for (int h8 = 0; h8 < 2; h8++) {
            u16x8 vv = *(const u16x8*)(vp + h8 * 8);
#pragma unroll
            for (int e = 0; e < 8; e++) o[h8 * 8 + e] += w * bf2f(vv[e]);
        }
    }

    // stage w_proj^T image (pure coalesced copy; conflict-free)
    const u16x8* wt = (const u16x8*)((const unsigned short*)(ws + WT_F_OFF));
#pragma unroll
    for (int it = 0; it < 8; it++) {
        int i = tid + it * 256;
        *((u16x8*)wl + i) = wt[i];
    }

    // write attention output to LDS [pl][c] bf16, 16B groups swizzled by pl&15
    {
        u16x8 lo, hi_;
#pragma unroll
        for (int e = 0; e < 8; e++) {
            lo[e]  = f2bf(o[e] * inv);
            hi_[e] = f2bf(o[8 + e] * inv);
        }
        int r15 = pl & 15;
        *(u16x8*)(aol + pl * 128 + (((head * 2)     ^ r15) << 3)) = lo;
        *(u16x8*)(aol + pl * 128 + (((head * 2 + 1) ^ r15) << 3)) = hi_;
    }
    __syncthreads();

    // proj GEMM: out[p][j] = sum_c' ao[p][c'] * wT[j][c']
    const int lane = tid & 63, wv = tid >> 6;
    const int col = lane & 15, kgrp = lane >> 4;
    const int ptile = wv & 1, jhalf = wv >> 1;
    const int arow = ptile * 16 + col;
    const unsigned short* ap = aol + arow * 128;
    u16x8 a[4];
#pragma unroll
    for (int ks = 0; ks < 4; ks++) {
        a[ks] = *(const u16x8*)(ap + (((ks * 4 + kgrp) ^ (arow & 15)) << 3));
    }
#pragma unroll
    for (int jt = 0; jt < 4; jt++) {
        int j = jhalf * 64 + jt * 16 + col;
        const unsigned short* bp = wl + j * 128;
        f32x4 acc = {0.f, 0.f, 0.f, 0.f};
#pragma unroll
        for (int ks = 0; ks < 4; ks++) {
            u16x8 b = *(const u16x8*)(bp + (((ks * 4 + kgrp) ^ (j & 15)) << 3));
            acc = __builtin_amdgcn_mfma_f32_16x16x32_bf16(
                    __builtin_bit_cast(bf16x8, a[ks]),
                    __builtin_bit_cast(bf16x8, b), acc, 0, 0, 0);
        }
        float bias = b_proj[j];
        float4 o4;
        o4.x = acc[0] + bias; o4.y = acc[1] + bias;
        o4.z = acc[2] + bias; o4.w = acc[3] + bias;
        *(float4*)(out + (size_t)j * HWZ + p0 + ptile * 16 + kgrp * 4) = o4;
    }
}

extern "C" void kernel_launch(void* const* d_in, const int* in_sizes, int n_in,
                              void* d_out, int out_size, void* d_ws, size_t ws_size,
                              hipStream_t stream) {
    const float* x      = (const float*)d_in[0];
    const float* w_qkv  = (const float*)d_in[1];
    const float* b_qkv  = (const float*)d_in[2];
    const float* rpb    = (const float*)d_in[3];
    const float* w_proj = (const float*)d_in[4];
    const float* b_proj = (const float*)d_in[5];
    float* out = (float*)d_out;
    float* ws  = (float*)d_ws;

    wprep_kernel<<<128, 128, 0, stream>>>(w_proj, ws);
    stats_kernel<<<128, 256, 0, stream>>>(x, ws);
    qkv_kernel<<<512, 512, 0, stream>>>(x, w_qkv, b_qkv, ws);
    attnproj_kernel<<<1024, 256, 0, stream>>>(rpb, b_proj, ws, out);
}